// Round 1
// baseline (127.815 us; speedup 1.0000x reference)
//
#include <hip/hip_runtime.h>
#include <hip/hip_bf16.h>

typedef __attribute__((ext_vector_type(8))) short bf16x8;
typedef __attribute__((ext_vector_type(4))) float f32x4;

// exp(v/T - 5) with T=0.2  ==  exp2( (v-1) * 5*log2(e) )
#define EXP_SCALE 7.213475204444817f

__device__ __forceinline__ float fast_exp2(float x) {
#if __has_builtin(__builtin_amdgcn_exp2f)
  return __builtin_amdgcn_exp2f(x);
#else
  return exp2f(x);
#endif
}

__device__ __forceinline__ unsigned short f32_to_bf16(float f) {
  unsigned int u = __float_as_uint(f);
  unsigned int r = (u + 0x7FFFu + ((u >> 16) & 1u)) >> 16;
  return (unsigned short)r;
}

// Kernel 1: L2-normalize rows of emb_i/emb_j -> z bf16 [8192][128].
// One wave per row; lane holds 2 floats.
__global__ __launch_bounds__(256) void k_normalize(
    const float* __restrict__ emb_i, const float* __restrict__ emb_j,
    unsigned short* __restrict__ z)
{
  const int w = threadIdx.x >> 6;
  const int lane = threadIdx.x & 63;
  const int row = (blockIdx.x << 2) + w;
  const float* src = (row < 4096) ? (emb_i + row * 128) : (emb_j + (row - 4096) * 128);
  float2 v = reinterpret_cast<const float2*>(src)[lane];
  float ss = v.x * v.x + v.y * v.y;
  #pragma unroll
  for (int m = 1; m < 64; m <<= 1) ss += __shfl_xor(ss, m, 64);
  float rinv = 1.0f / sqrtf(ss);
  ushort2 st;
  st.x = f32_to_bf16(v.x * rinv);
  st.y = f32_to_bf16(v.y * rinv);
  reinterpret_cast<ushort2*>(z + row * 128)[lane] = st;
}

// Kernel 2: per 32-row tile x col-half, accumulate sum_k exp(l-5) (diag excluded)
// and capture positive logits. 4 waves split col tiles; MFMA 16x16x32 bf16.
// A-frag: A[m=lane&15][k=(lane>>4)*8+j]; B-frag same with n=lane&15.
// C/D: col=lane&15, row=(lane>>4)*4+reg  (m89-verified layout).
__global__ __launch_bounds__(256) void k_simlse(
    const unsigned short* __restrict__ z,
    float* __restrict__ rowsum,   // [2][8192]
    float* __restrict__ rowpos)   // [8192]
{
  const int w = threadIdx.x >> 6;
  const int lane = threadIdx.x & 63;
  const int q = lane >> 4;
  const int c = lane & 15;
  const int rt = blockIdx.x >> 1;
  const int ch = blockIdx.x & 1;
  const int R0 = rt << 5;

  bf16x8 a[2][4];
  #pragma unroll
  for (int rg = 0; rg < 2; ++rg) {
    const unsigned short* ap = z + (R0 + (rg << 4) + c) * 128 + (q << 3);
    #pragma unroll
    for (int kk = 0; kk < 4; ++kk)
      a[rg][kk] = *reinterpret_cast<const bf16x8*>(ap + (kk << 5));
  }

  float acc[2][4] = {0.f, 0.f, 0.f, 0.f, 0.f, 0.f, 0.f, 0.f};
  float pacc[2][4] = {0.f, 0.f, 0.f, 0.f, 0.f, 0.f, 0.f, 0.f};
  const int diag0 = R0 >> 4;                      // diag tile for rg=0 (rg=1 is +1)
  const int pos0  = ((R0 + 4096) & 8191) >> 4;    // pos tile for rg=0

  #pragma unroll 2
  for (int i = 0; i < 64; ++i) {
    const int ct = (ch << 8) + (i << 2) + w;      // global 16-col tile index
    const unsigned short* bp = z + ((ct << 4) + c) * 128 + (q << 3);
    bf16x8 b0 = *reinterpret_cast<const bf16x8*>(bp);
    bf16x8 b1 = *reinterpret_cast<const bf16x8*>(bp + 32);
    bf16x8 b2 = *reinterpret_cast<const bf16x8*>(bp + 64);
    bf16x8 b3 = *reinterpret_cast<const bf16x8*>(bp + 96);
    f32x4 c0 = {0.f, 0.f, 0.f, 0.f}, c1 = {0.f, 0.f, 0.f, 0.f};
    c0 = __builtin_amdgcn_mfma_f32_16x16x32_bf16(a[0][0], b0, c0, 0, 0, 0);
    c1 = __builtin_amdgcn_mfma_f32_16x16x32_bf16(a[1][0], b0, c1, 0, 0, 0);
    c0 = __builtin_amdgcn_mfma_f32_16x16x32_bf16(a[0][1], b1, c0, 0, 0, 0);
    c1 = __builtin_amdgcn_mfma_f32_16x16x32_bf16(a[1][1], b1, c1, 0, 0, 0);
    c0 = __builtin_amdgcn_mfma_f32_16x16x32_bf16(a[0][2], b2, c0, 0, 0, 0);
    c1 = __builtin_amdgcn_mfma_f32_16x16x32_bf16(a[1][2], b2, c1, 0, 0, 0);
    c0 = __builtin_amdgcn_mfma_f32_16x16x32_bf16(a[0][3], b3, c0, 0, 0, 0);
    c1 = __builtin_amdgcn_mfma_f32_16x16x32_bf16(a[1][3], b3, c1, 0, 0, 0);

    const bool special = ((unsigned)(ct - diag0) <= 1u) | ((unsigned)(ct - pos0) <= 1u);
    if (!special) {  // wave-uniform branch; hot path
      #pragma unroll
      for (int e = 0; e < 4; ++e) {
        acc[0][e] += fast_exp2(EXP_SCALE * (c0[e] - 1.0f));
        acc[1][e] += fast_exp2(EXP_SCALE * (c1[e] - 1.0f));
      }
    } else {
      #pragma unroll
      for (int rg = 0; rg < 2; ++rg) {
        const f32x4 cc = rg ? c1 : c0;
        const bool isdiag = (ct == diag0 + rg);
        const bool ispos  = (ct == pos0 + rg);
        #pragma unroll
        for (int e = 0; e < 4; ++e) {
          float v = cc[e];
          bool self = (c == ((q << 2) + e));   // tile-diagonal element
          float t = fast_exp2(EXP_SCALE * (v - 1.0f));
          if (isdiag && self) t = 0.0f;        // exclude k==i
          acc[rg][e] += t;
          if (ispos && self) pacc[rg][e] = v * 5.0f;  // pos logit = v/T
        }
      }
    }
  }

  // sum across the 16 lanes sharing a row (xor masks 1..8 stay in the group)
  #pragma unroll
  for (int m = 1; m < 16; m <<= 1) {
    #pragma unroll
    for (int rg = 0; rg < 2; ++rg)
      #pragma unroll
      for (int e = 0; e < 4; ++e) {
        acc[rg][e]  += __shfl_xor(acc[rg][e],  m, 64);
        pacc[rg][e] += __shfl_xor(pacc[rg][e], m, 64);
      }
  }

  __shared__ float lsum[4][32];
  __shared__ float lpos[4][32];
  if (c == 0) {
    #pragma unroll
    for (int rg = 0; rg < 2; ++rg)
      #pragma unroll
      for (int e = 0; e < 4; ++e) {
        int rr = (rg << 4) + (q << 2) + e;
        lsum[w][rr] = acc[rg][e];
        lpos[w][rr] = pacc[rg][e];
      }
  }
  __syncthreads();
  if (threadIdx.x < 32) {
    const int r = R0 + threadIdx.x;
    float s = lsum[0][threadIdx.x] + lsum[1][threadIdx.x] +
              lsum[2][threadIdx.x] + lsum[3][threadIdx.x];
    rowsum[(ch << 13) + r] = s;
    if (ch != (R0 >> 12)) {   // this col-half owns the positive column
      float p = lpos[0][threadIdx.x] + lpos[1][threadIdx.x] +
                lpos[2][threadIdx.x] + lpos[3][threadIdx.x];
      rowpos[r] = p;
    }
  }
}

// Kernel 3: lse = 5 + log(sum), loss = mean(lse - pos). Single block, plain store.
__global__ __launch_bounds__(1024) void k_finish(
    const float* __restrict__ rowsum, const float* __restrict__ rowpos,
    float* __restrict__ out)
{
  float s = 0.0f;
  for (int r = threadIdx.x; r < 8192; r += 1024) {
    float tot = rowsum[r] + rowsum[8192 + r];
    float lse = 5.0f + logf(tot);
    s += lse - rowpos[r];
  }
  #pragma unroll
  for (int m = 1; m < 64; m <<= 1) s += __shfl_xor(s, m, 64);
  __shared__ float red[16];
  if ((threadIdx.x & 63) == 0) red[threadIdx.x >> 6] = s;
  __syncthreads();
  if (threadIdx.x == 0) {
    float t = 0.f;
    #pragma unroll
    for (int i = 0; i < 16; ++i) t += red[i];
    out[0] = t * (1.0f / 8192.0f);
  }
}

extern "C" void kernel_launch(void* const* d_in, const int* in_sizes, int n_in,
                              void* d_out, int out_size, void* d_ws, size_t ws_size,
                              hipStream_t stream) {
  const float* emb_i = (const float*)d_in[0];
  const float* emb_j = (const float*)d_in[1];
  unsigned short* z = (unsigned short*)d_ws;                       // 8192*128*2 = 2 MB
  float* rowsum = (float*)((char*)d_ws + 8192 * 128 * 2);          // [2][8192] = 64 KB
  float* rowpos = rowsum + 2 * 8192;                               // [8192] = 32 KB
  float* out = (float*)d_out;

  k_normalize<<<2048, 256, 0, stream>>>(emb_i, emb_j, z);
  k_simlse<<<512, 256, 0, stream>>>(z, rowsum, rowpos);
  k_finish<<<1, 1024, 0, stream>>>(rowsum, rowpos, out);
}

// Round 2
// 99.300 us; speedup vs baseline: 1.2872x; 1.2872x over previous
//
#include <hip/hip_runtime.h>
#include <hip/hip_bf16.h>

typedef __attribute__((ext_vector_type(8))) short bf16x8;
typedef __attribute__((ext_vector_type(4))) float f32x4;

// exp(v/T - 5) with T=0.2  ==  exp2( (v-1) * 5*log2(e) )
#define EXP_SCALE 7.213475204444817f

__device__ __forceinline__ float fast_exp2(float x) {
#if __has_builtin(__builtin_amdgcn_exp2f)
  return __builtin_amdgcn_exp2f(x);
#else
  return exp2f(x);
#endif
}

__device__ __forceinline__ unsigned short f32_to_bf16(float f) {
  unsigned int u = __float_as_uint(f);
  unsigned int r = (u + 0x7FFFu + ((u >> 16) & 1u)) >> 16;
  return (unsigned short)r;
}

// Kernel 1: L2-normalize rows of emb_i/emb_j -> z bf16 [8192][128].
// One wave per row; lane holds 2 floats. Also zeroes out[0] (stream-ordered
// before k_finish's atomics; harness poisons d_out before every launch).
__global__ __launch_bounds__(256) void k_normalize(
    const float* __restrict__ emb_i, const float* __restrict__ emb_j,
    unsigned short* __restrict__ z, float* __restrict__ out)
{
  if (blockIdx.x == 0 && threadIdx.x == 0) out[0] = 0.0f;
  const int w = threadIdx.x >> 6;
  const int lane = threadIdx.x & 63;
  const int row = (blockIdx.x << 2) + w;
  const float* src = (row < 4096) ? (emb_i + row * 128) : (emb_j + (row - 4096) * 128);
  float2 v = reinterpret_cast<const float2*>(src)[lane];
  float ss = v.x * v.x + v.y * v.y;
  #pragma unroll
  for (int m = 1; m < 64; m <<= 1) ss += __shfl_xor(ss, m, 64);
  float rinv = 1.0f / sqrtf(ss);
  ushort2 st;
  st.x = f32_to_bf16(v.x * rinv);
  st.y = f32_to_bf16(v.y * rinv);
  reinterpret_cast<ushort2*>(z + row * 128)[lane] = st;
}

// Kernel 2: block = 64 rows x 1024-col chunk. 4 waves each own ALL 64 rows
// (A in regs: 16 bf16x8) and split the 64 cols/iter into 4x 16-col B tiles.
// 16 MFMAs per 4 B-loads; B for iter i+1 prefetched into registers during
// iter i's MFMAs. Grid = 128 row-blocks x 8 col-chunks = 1024.
// A-frag: A[m=lane&15][k=(lane>>4)*8+j]; B same with n=lane&15.
// C/D: col=lane&15, row=(lane>>4)*4+reg (m89-verified).
__global__ __launch_bounds__(256, 3) void k_simlse(
    const unsigned short* __restrict__ z,
    float* __restrict__ rowsum,   // [8][8192]
    float* __restrict__ rowpos)   // [8192]
{
  const int w = threadIdx.x >> 6;
  const int lane = threadIdx.x & 63;
  const int q = lane >> 4;
  const int c = lane & 15;
  const int rb = blockIdx.x >> 3;       // 0..127
  const int ch = blockIdx.x & 7;        // 0..7
  const int R0 = rb << 6;               // 64-row block

  // A fragments: rows R0..R0+63, all K=128 (4 chunks of 32)
  bf16x8 a[4][4];
  #pragma unroll
  for (int rg = 0; rg < 4; ++rg) {
    const unsigned short* ap = z + (R0 + (rg << 4) + c) * 128 + (q << 3);
    #pragma unroll
    for (int kk = 0; kk < 4; ++kk)
      a[rg][kk] = *reinterpret_cast<const bf16x8*>(ap + (kk << 5));
  }

  float acc[4][4];
  #pragma unroll
  for (int rg = 0; rg < 4; ++rg)
    #pragma unroll
    for (int e = 0; e < 4; ++e) acc[rg][e] = 0.0f;
  float pacc[4] = {0.f, 0.f, 0.f, 0.f};

  const int diag0 = R0 >> 4;                      // diag tile for rg (==diag0+rg)
  const int pos0  = ((R0 + 4096) & 8191) >> 4;    // pos tile for rg (==pos0+rg)

  const int ct0 = (ch << 6) + w;                  // this wave's first 16-col tile
  const unsigned short* bp = z + ((ct0 << 4) + c) * 128 + (q << 3);

  bf16x8 bc[4], bn[4];
  #pragma unroll
  for (int kk = 0; kk < 4; ++kk)
    bc[kk] = *reinterpret_cast<const bf16x8*>(bp + (kk << 5));

  auto process = [&](int i) {
    const int ct = ct0 + (i << 2);
    f32x4 cc[4];
    #pragma unroll
    for (int rg = 0; rg < 4; ++rg) cc[rg] = f32x4{0.f, 0.f, 0.f, 0.f};
    #pragma unroll
    for (int kk = 0; kk < 4; ++kk)
      #pragma unroll
      for (int rg = 0; rg < 4; ++rg)
        cc[rg] = __builtin_amdgcn_mfma_f32_16x16x32_bf16(a[rg][kk], bc[kk], cc[rg], 0, 0, 0);
    #pragma unroll
    for (int rg = 0; rg < 4; ++rg)
      #pragma unroll
      for (int e = 0; e < 4; ++e)
        acc[rg][e] += fast_exp2(EXP_SCALE * (cc[rg][e] - 1.0f));
    // Special tiles: only rg with ct==diag0+rg / ct==pos0+rg (provably rg==w).
    // Compile-time rg indices; rare wave-uniform branches.
    #pragma unroll
    for (int rg = 0; rg < 4; ++rg) {
      if (ct == diag0 + rg) {
        #pragma unroll
        for (int e = 0; e < 4; ++e)
          if (c == ((q << 2) + e))
            acc[rg][e] -= fast_exp2(EXP_SCALE * (cc[rg][e] - 1.0f));
      }
      if (ct == pos0 + rg) {
        #pragma unroll
        for (int e = 0; e < 4; ++e)
          if (c == ((q << 2) + e)) pacc[e] = cc[rg][e] * 5.0f;
      }
    }
  };

  #pragma unroll 2
  for (int i = 0; i < 15; ++i) {
    const unsigned short* bnp = bp + 8192;  // +64 rows of 128 shorts
    #pragma unroll
    for (int kk = 0; kk < 4; ++kk)
      bn[kk] = *reinterpret_cast<const bf16x8*>(bnp + (kk << 5));
    process(i);
    #pragma unroll
    for (int kk = 0; kk < 4; ++kk) bc[kk] = bn[kk];
    bp = bnp;
  }
  process(15);

  // Reduce over the 16 cols (c-group: xor masks 1,2,4,8)
  #pragma unroll
  for (int m = 1; m < 16; m <<= 1) {
    #pragma unroll
    for (int rg = 0; rg < 4; ++rg)
      #pragma unroll
      for (int e = 0; e < 4; ++e)
        acc[rg][e] += __shfl_xor(acc[rg][e], m, 64);
    #pragma unroll
    for (int e = 0; e < 4; ++e) pacc[e] += __shfl_xor(pacc[e], m, 64);
  }

  __shared__ float lsum[4][64];
  __shared__ float lpos[4][16];
  if (c == 0) {
    #pragma unroll
    for (int rg = 0; rg < 4; ++rg)
      #pragma unroll
      for (int e = 0; e < 4; ++e)
        lsum[w][(rg << 4) + (q << 2) + e] = acc[rg][e];
    #pragma unroll
    for (int e = 0; e < 4; ++e) lpos[w][(q << 2) + e] = pacc[e];
  }
  __syncthreads();
  if (threadIdx.x < 64) {
    const int t = threadIdx.x;
    const int r = R0 + t;
    float s = lsum[0][t] + lsum[1][t] + lsum[2][t] + lsum[3][t];
    rowsum[(ch << 13) + r] = s;
    const int P = (R0 + 4096) & 8191;
    if (ch == (P >> 10))                 // this chunk owns the positive cols
      rowpos[r] = lpos[t >> 4][t & 15];  // pos for local row t came from wave t>>4
  }
}

// Kernel 3: lse = 5 + log(sum over 8 chunks), loss = mean(lse - pos).
// 32 blocks x 256 threads; atomicAdd partials into out (zeroed by k_normalize).
__global__ __launch_bounds__(256) void k_finish(
    const float* __restrict__ rowsum, const float* __restrict__ rowpos,
    float* __restrict__ out)
{
  const int r = blockIdx.x * 256 + threadIdx.x;
  float tot = 0.0f;
  #pragma unroll
  for (int chunk = 0; chunk < 8; ++chunk) tot += rowsum[(chunk << 13) + r];
  float v = 5.0f + logf(tot) - rowpos[r];
  #pragma unroll
  for (int m = 1; m < 64; m <<= 1) v += __shfl_xor(v, m, 64);
  __shared__ float red[4];
  if ((threadIdx.x & 63) == 0) red[threadIdx.x >> 6] = v;
  __syncthreads();
  if (threadIdx.x == 0)
    atomicAdd(out, (red[0] + red[1] + red[2] + red[3]) * (1.0f / 8192.0f));
}

extern "C" void kernel_launch(void* const* d_in, const int* in_sizes, int n_in,
                              void* d_out, int out_size, void* d_ws, size_t ws_size,
                              hipStream_t stream) {
  const float* emb_i = (const float*)d_in[0];
  const float* emb_j = (const float*)d_in[1];
  unsigned short* z = (unsigned short*)d_ws;                       // 8192*128*2 = 2 MB
  float* rowsum = (float*)((char*)d_ws + 8192 * 128 * 2);          // [8][8192] = 256 KB
  float* rowpos = rowsum + 8 * 8192;                               // [8192] = 32 KB
  float* out = (float*)d_out;

  k_normalize<<<2048, 256, 0, stream>>>(emb_i, emb_j, z, out);
  k_simlse<<<1024, 256, 0, stream>>>(z, rowsum, rowpos);
  k_finish<<<32, 256, 0, stream>>>(rowsum, rowpos, out);
}